// Round 15
// baseline (186.412 us; speedup 1.0000x reference)
//
#include <hip/hip_runtime.h>
#include <cstdint>
#include <math.h>

// Canny_1116691497316: per-channel Canny edges, out = x[:,indices] * tf
// x: (1,64,512,512) f32, indices: (32,) int32, out: (1,32,512,512) f32
//
// Round 15: round-14 f32 pipeline (canny_fused verbatim, minus two provably
// unnecessary axis-flag terms) + compact-then-recheck fixup:
//   compact_kernel: flag bitmap -> dense pixel list (wave-aggregated atomics)
//   fixup_kernel:   one thread per flagged pixel, f64 recheck (r7-11 chains)
// Pipeline: memset(fcount) -> canny_fused -> compact -> fixup -> hyst -> mul.

constexpr int HH = 512;
constexpr int WW = 512;
constexpr int HW = HH * WW;          // 262144 px per channel
constexpr int KCH = 32;              // selected channels
constexpr int WORDS = HW / 32;       // 8192 uint32 words per bitmap per channel

constexpr int TD = 32;               // tile dim
constexpr int NT = HH / TD;          // 16

constexpr int IN_D = 40;             // input tile 40x40 (halo 4)
constexpr int VP_C = 40;             // vp tile 36x40
constexpr int BL_D = 36;             // blur tile 36x36
constexpr int SQ_D = 34;             // mag^2 tile 34x34

constexpr unsigned int LISTCAP = 262144;   // flag-list capacity (1 MB)

// f64 gaussian weights, exact value chain of the reference
constexpr double E2 = 0.13533528323661269189;  // exp(-2.0)
constexpr double E1 = 0.60653065971263342360;  // exp(-0.5)
constexpr double GS = ((((E2 + E1) + 1.0) + E1) + E2);
constexpr double GW0 = E2 / GS, GW1 = E1 / GS, GW2 = 1.0 / GS;

constexpr double T1 = 0.4142135623730950488;   // tan(22.5deg)
constexpr double T2 = 2.4142135623730950488;   // tan(67.5deg)
constexpr double SQ_HI = 0.2 * 0.2;
constexpr double SQ_LO = 0.1 * 0.1;

__device__ __forceinline__ int reflect_idx(int v) {
    return v < 0 ? -v : (v > 511 ? 1022 - v : v);
}
__device__ __forceinline__ int clampi(int v) {
    return v < 0 ? 0 : (v > 511 ? 511 : v);
}

// axis a in {0..3}: NMS neighbor pair, == rint(atan2(gy,gx)*(180/pi)/45) mod 4
__device__ const int AY1[4] = {0, 1, 1, 1};
__device__ const int AX1[4] = {1, 1, 0, -1};

// ---------------- Kernel 1: fused f32 blur + sobel + mag^2 + NMS + flag ballot ----------------
// (round-14 structure verbatim; only the two unnecessary axis-flag terms removed)
__global__ __launch_bounds__(256) void canny_fused(const float* __restrict__ x,
                                                   const int* __restrict__ idx,
                                                   unsigned int* __restrict__ weakb,
                                                   unsigned int* __restrict__ strongb,
                                                   unsigned int* __restrict__ flagb) {
    __shared__ __align__(16) char lds[13504];
    float* vp_s = (float*)lds;                             // [36*40]
    float* sq_s = (float*)lds;                             // [34*34] overlay
    float* in_s = (float*)(lds + 5760);                    // [40*40]
    float* bl_s = (float*)(lds + 5760);                    // [36*36] overlay
    unsigned char* ax_s = (unsigned char*)(lds + 12160);   // [32*32]
    unsigned char* RUm = (unsigned char*)(lds + 13184);    // [34]
    unsigned char* RDm = RUm + 34;
    unsigned char* CLm = RUm + 68;
    unsigned char* CRm = RUm + 102;
    unsigned short* rmap = (unsigned short*)(lds + 13320); // [40]
    unsigned short* cmap = rmap + 40;                      // [40]

    int tile = blockIdx.x;
    int k = tile >> 8;                 // 256 tiles per channel
    int t = tile & 255;
    int ty0 = (t >> 4) * TD;
    int tx0 = (t & 15) * TD;
    int tid = threadIdx.x;

    int ch = idx[k];
    const float* img = x + (size_t)ch * HW;

    // ---- index tables ----
    if (tid < 40) {
        rmap[tid] = (unsigned short)reflect_idx(ty0 - 4 + tid);
        cmap[tid] = (unsigned short)reflect_idx(tx0 - 4 + tid);
    } else if (tid >= 64 && tid < 98) {
        int am = tid - 64;
        int u = ty0 - 1 + am;
        RUm[am] = (unsigned char)(clampi(u - 1) - (ty0 - 2));
        RDm[am] = (unsigned char)(clampi(u + 1) - (ty0 - 2));
    } else if (tid >= 128 && tid < 162) {
        int bm = tid - 128;
        int v = tx0 - 1 + bm;
        CLm[bm] = (unsigned char)(clampi(v - 1) - (tx0 - 2));
        CRm[bm] = (unsigned char)(clampi(v + 1) - (tx0 - 2));
    }
    __syncthreads();   // load below consumes rmap/cmap cross-wave

    // ---- load input tile 40x40 via reflect maps ----
    {
        int a = tid / 40, b = tid - (tid / 40) * 40;
        while (a < 40) {
            in_s[a * IN_D + b] = img[(int)rmap[a] * WW + (int)cmap[b]];
            b += 16; a += 6;
            if (b >= 40) { b -= 40; a += 1; }
        }
    }
    __syncthreads();

    const float g0 = (float)GW0, g1 = (float)GW1, g2 = (float)GW2;

    // ---- vertical blur (f32): sliding window, lane-major columns ----
    if (tid < 240) {
        int rg = tid / 40;
        int b = tid - 40 * rg;
        int a0 = 6 * rg;
        float w[10];
        #pragma unroll
        for (int j = 0; j < 10; j++) w[j] = in_s[(a0 + j) * IN_D + b];
        #pragma unroll
        for (int i = 0; i < 6; i++) {
            float acc = g0 * w[i];
            acc += g1 * w[i + 1];
            acc += g2 * w[i + 2];
            acc += g1 * w[i + 3];
            acc += g0 * w[i + 4];
            vp_s[(a0 + i) * VP_C + b] = acc;
        }
    }
    __syncthreads();

    // ---- horizontal blur (f32): per-cell linear ----
    {
        int a = tid / 36, b = tid - 36 * (tid / 36);
        while (a < 36) {
            const float* vr = vp_s + a * VP_C + b;
            float acc = g0 * vr[0];
            acc += g1 * vr[1];
            acc += g2 * vr[2];
            acc += g1 * vr[3];
            acc += g0 * vr[4];
            bl_s[a * BL_D + b] = acc;
            b += 4; a += 7;
            if (b >= 36) { b -= 36; a += 1; }
        }
    }
    __syncthreads();   // fences vp reads before sq overlay writes

    // ---- mag^2 + axis (f32), axis-borderline flag in bit 2 ----
    const float T1f = (float)T1, T2f = (float)T2;
    {
        int am = tid / 34, bm = tid - 34 * (tid / 34);
        while (am < 34) {
            int ru = RUm[am], r0 = am + 1, rd = RDm[am];
            int cl = CLm[bm], c0 = bm + 1, cr = CRm[bm];
            float v00 = bl_s[ru * BL_D + cl], v01 = bl_s[ru * BL_D + c0], v02 = bl_s[ru * BL_D + cr];
            float v10 = bl_s[r0 * BL_D + cl],                              v12 = bl_s[r0 * BL_D + cr];
            float v20 = bl_s[rd * BL_D + cl], v21 = bl_s[rd * BL_D + c0], v22 = bl_s[rd * BL_D + cr];
            float gxv = ((((-v00 + v02) + (-2.0f * v10)) + (2.0f * v12)) + (-v20)) + v22;
            float gyv = ((((-v00 + (-2.0f * v01)) + (-v02)) + v20) + (2.0f * v21)) + v22;
            sq_s[am * SQ_D + bm] = (gxv * gxv + gyv * gyv) + 1e-6f;

            float axf = fabsf(gxv), ayf = fabsf(gyv);
            int axis;
            if (ayf < T1f * axf) axis = 0;
            else if (ayf > T2f * axf) axis = 2;
            else {
                float gxf = (gyv < 0.0f) ? -gxv : gxv;
                axis = (gxf > 0.0f) ? 1 : 3;
            }
            // flag only genuine T1/T2 boundary bands. |g| tiny cases are
            // provably decision-invariant (see round-15 notes).
            float mrg = 3e-4f * (axf + ayf);
            int aflag = ((fabsf(ayf - T1f * axf) <= mrg) |
                         (fabsf(ayf - T2f * axf) <= mrg)) ? 4 : 0;
            if (am >= 1 && am <= TD && bm >= 1 && bm <= TD)
                ax_s[(am - 1) * TD + (bm - 1)] = (unsigned char)(axis | aflag);

            bm += 18; am += 7;
            if (bm >= 34) { bm -= 34; am += 1; }
        }
    }
    __syncthreads();

    // ---- NMS + thresholds (f32) + branch-free flag ballot ----
    #pragma unroll
    for (int q4 = 0; q4 < TD * TD / 256; q4++) {
        int l = q4 * 256 + tid;
        int oy = l >> 5, ox = l & 31;
        int gy = ty0 + oy, gx = tx0 + ox;

        unsigned char av = ax_s[oy * TD + ox];
        int axis = av & 3;
        int dy = AY1[axis], dx = AX1[axis];
        float s = sq_s[(oy + 1) * SQ_D + (ox + 1)];

        int y1 = gy + dy, x1 = gx + dx;
        int y2 = gy - dy, x2 = gx - dx;
        bool in1 = (y1 >= 0) && (y1 < HH) && (x1 >= 0) && (x1 < WW);
        bool in2 = (y2 >= 0) && (y2 < HH) && (x2 >= 0) && (x2 < WW);
        float s1 = in1 ? sq_s[(oy + 1 + dy) * SQ_D + (ox + 1 + dx)] : 0.0f;
        float s2 = in2 ? sq_s[(oy + 1 - dy) * SQ_D + (ox + 1 - dx)] : 0.0f;
        bool keep = (s > s1) && (s > s2);
        bool strong = keep && (s > 0.04f);
        bool weak = keep && (s > 0.01f) && !strong;

        const float e = 3e-4f;
        bool flag = (av & 4) != 0;
        flag = flag | (in1 & (fabsf(s - s1) <= e * (s + s1)));
        flag = flag | (in2 & (fabsf(s - s2) <= e * (s + s2)));
        flag = flag | (fabsf(s - 0.04f) <= e * (s + 0.04f));
        flag = flag | (fabsf(s - 0.01f) <= e * (s + 0.01f));

        unsigned long long wb = __ballot(weak);
        unsigned long long sb = __ballot(strong);
        unsigned long long fb = __ballot(flag);
        if ((tid & 31) == 0) {
            unsigned int ww = (tid & 32) ? (unsigned int)(wb >> 32) : (unsigned int)wb;
            unsigned int sw = (tid & 32) ? (unsigned int)(sb >> 32) : (unsigned int)sb;
            unsigned int fw = (tid & 32) ? (unsigned int)(fb >> 32) : (unsigned int)fb;
            size_t w32 = ((size_t)k * HW + (size_t)gy * WW + tx0) >> 5;
            weakb[w32] = ww;
            strongb[w32] = sw;
            flagb[w32] = fw;
        }
    }
}

// ---------------- Kernel 2: compact flag bitmap -> dense pixel list ----------------
// One thread per word; wave-aggregated atomicAdd (one per wave with flags).
__global__ __launch_bounds__(256) void compact_kernel(const unsigned int* __restrict__ flagb,
                                                      unsigned int* __restrict__ fcount,
                                                      unsigned int* __restrict__ flist) {
    unsigned int w = blockIdx.x * 256 + threadIdx.x;   // 0..262143
    unsigned int f = flagb[w];
    unsigned int n = (unsigned int)__popc(f);
    int lane = threadIdx.x & 63;

    // 64-lane inclusive prefix sum of n
    unsigned int xs = n;
    #pragma unroll
    for (int off = 1; off < 64; off <<= 1) {
        unsigned int y = __shfl_up(xs, off);
        if (lane >= off) xs += y;
    }
    unsigned int total = __shfl(xs, 63);
    unsigned int base = 0;
    if (total) {
        if (lane == 63) base = atomicAdd(fcount, total);
        base = __shfl(base, 63);
    }
    unsigned int pos = base + xs - n;
    while (f) {
        int b = __ffs(f) - 1;
        f &= f - 1;
        if (pos < LISTCAP) flist[pos] = (w << 5) | (unsigned int)b;
        pos++;
    }
}

// ---------------- Kernel 3: f64 fixup, one thread per flagged pixel ----------------
__device__ double blur64g(const float* __restrict__ img, int iy, int ix) {
    const double G[5] = {GW0, GW1, GW2, GW1, GW0};
    double acc = 0.0;
    #pragma unroll
    for (int i = 0; i < 5; i++) {
        double col = 0.0;
        #pragma unroll
        for (int j = 0; j < 5; j++)
            col += G[j] * (double)img[reflect_idx(iy - 2 + j) * WW + reflect_idx(ix - 2 + i)];
        acc += G[i] * col;
    }
    return acc;
}
__device__ void sobel64g(const float* __restrict__ img, int py, int px,
                         double& gxv, double& gyv) {
    int ru = clampi(py - 1), r0 = py, rd = clampi(py + 1);
    int cl = clampi(px - 1), c0 = px, cr = clampi(px + 1);
    double v00 = blur64g(img, ru, cl), v01 = blur64g(img, ru, c0), v02 = blur64g(img, ru, cr);
    double v10 = blur64g(img, r0, cl),                              v12 = blur64g(img, r0, cr);
    double v20 = blur64g(img, rd, cl), v21 = blur64g(img, rd, c0), v22 = blur64g(img, rd, cr);
    gxv = ((((-v00 + v02) + (-2.0 * v10)) + (2.0 * v12)) + (-v20)) + v22;
    gyv = ((((-v00 + (-2.0 * v01)) + (-v02)) + v20) + (2.0 * v21)) + v22;
}

__global__ __launch_bounds__(256) void fixup_kernel(const float* __restrict__ x,
                                                    const int* __restrict__ idx,
                                                    const unsigned int* __restrict__ fcount,
                                                    const unsigned int* __restrict__ flist,
                                                    unsigned int* __restrict__ weakb,
                                                    unsigned int* __restrict__ strongb) {
    unsigned int n = *fcount;
    if (n > LISTCAP) n = LISTCAP;
    unsigned int i = blockIdx.x * 256 + threadIdx.x;
    if (i >= n) return;

    unsigned int p = flist[i];
    int k = (int)(p >> 18);
    int gy = (int)((p >> 9) & 511);
    int gx = (int)(p & 511);
    const float* img = x + (size_t)idx[k] * HW;

    double gxc, gyc;
    sobel64g(img, gy, gx, gxc, gyc);
    double s = (gxc * gxc + gyc * gyc) + 1e-6;

    double ax = fabs(gxc), ay = fabs(gyc);
    int axis;
    if (ay < T1 * ax) axis = 0;
    else if (ay > T2 * ax) axis = 2;
    else {
        double gxf = (gyc < 0.0) ? -gxc : gxc;
        axis = (gxf > 0.0) ? 1 : 3;
    }
    int dy = AY1[axis], dx = AX1[axis];

    double s1 = 0.0, s2 = 0.0, tx, ty;
    int y1 = gy + dy, x1 = gx + dx, y2 = gy - dy, x2 = gx - dx;
    if (y1 >= 0 && y1 < HH && x1 >= 0 && x1 < WW) {
        sobel64g(img, y1, x1, tx, ty);
        s1 = (tx * tx + ty * ty) + 1e-6;
    }
    if (y2 >= 0 && y2 < HH && x2 >= 0 && x2 < WW) {
        sobel64g(img, y2, x2, tx, ty);
        s2 = (tx * tx + ty * ty) + 1e-6;
    }
    bool keep = (s > s1) && (s > s2);
    bool strong = keep && (s > SQ_HI);
    bool weak = keep && (s > SQ_LO) && !strong;

    size_t pw = (size_t)k * HW + (size_t)gy * WW + gx;
    unsigned int m = 1u << (pw & 31);
    size_t w = pw >> 5;
    if (weak) atomicOr(&weakb[w], m); else atomicAnd(&weakb[w], ~m);
    if (strong) atomicOr(&strongb[w], m); else atomicAnd(&strongb[w], ~m);
}

// ---------------- Kernel 4: hysteresis closure on bitmaps ----------------
__global__ __launch_bounds__(1024) void hyst_iterate(const unsigned int* __restrict__ weakb,
                                                     unsigned int* __restrict__ strongb) {
    int k = blockIdx.x;
    __shared__ unsigned int Sm[WORDS];
    __shared__ int s_changed;
    int tid = threadIdx.x;

    const unsigned int* wsrc = weakb + (size_t)k * WORDS;
    unsigned int* ssrc = strongb + (size_t)k * WORDS;

    if (tid == 0) s_changed = 0;
    for (int i = tid; i < WORDS; i += 1024) Sm[i] = ssrc[i];
    unsigned int wreg[8];
    #pragma unroll
    for (int q = 0; q < 8; q++) wreg[q] = wsrc[tid * 8 + q];
    __syncthreads();

    for (;;) {
        int loc = 0;
        #pragma unroll
        for (int q = 0; q < 8; q++) {
            int w = tid * 8 + q;
            unsigned int s = Sm[w];
            unsigned int wk = wreg[q] & ~s;
            if (!wk) continue;
            int j = w & 15;
            unsigned int L = j ? Sm[w - 1] : 0u;
            unsigned int R = (j < 15) ? Sm[w + 1] : 0u;
            unsigned int D = (s << 1) | (L >> 31) | (s >> 1) | (R << 31);
            if (w >= 16) {
                unsigned int cu = Sm[w - 16];
                unsigned int Lu = j ? Sm[w - 17] : 0u;
                unsigned int Ru = (j < 15) ? Sm[w - 15] : 0u;
                D |= cu | (cu << 1) | (Lu >> 31) | (cu >> 1) | (Ru << 31);
            }
            if (w < WORDS - 16) {
                unsigned int cd = Sm[w + 16];
                unsigned int Ld = j ? Sm[w + 15] : 0u;
                unsigned int Rd = (j < 15) ? Sm[w + 17] : 0u;
                D |= cd | (cd << 1) | (Ld >> 31) | (cd >> 1) | (Rd << 31);
            }
            unsigned int promoted = wk & D;
            if (promoted) { Sm[w] = s | promoted; loc = 1; }
        }
        if (loc) s_changed = 1;
        __syncthreads();
        int chg = s_changed;
        __syncthreads();
        if (!chg) break;
        if (tid == 0) s_changed = 0;
        __syncthreads();
    }

    for (int i = tid; i < WORDS; i += 1024) ssrc[i] = Sm[i];
}

// ---------------- Kernel 5: out = x[:,indices] * tf, full grid, float4 ----------------
__global__ void mul_kernel(const float* __restrict__ x,
                           const int* __restrict__ idx,
                           const unsigned int* __restrict__ weakb,
                           const unsigned int* __restrict__ strongb,
                           float* __restrict__ out) {
    int gid = blockIdx.x * blockDim.x + threadIdx.x;
    int p = gid * 4;
    if (p >= KCH * HW) return;
    int k = p >> 18;
    int r = p & (HW - 1);
    int ch = idx[k];

    unsigned int sw = strongb[p >> 5];
    unsigned int ww = weakb[p >> 5];
    int b0 = p & 31;

    const float4 xv = *reinterpret_cast<const float4*>(x + (size_t)ch * HW + r);
    float t[4];
    #pragma unroll
    for (int i = 0; i < 4; i++) {
        int b = b0 + i;
        t[i] = ((sw >> b) & 1u) ? 1.0f : (((ww >> b) & 1u) ? 0.5f : 0.0f);
    }
    float4 o;
    o.x = xv.x * t[0];
    o.y = xv.y * t[1];
    o.z = xv.z * t[2];
    o.w = xv.w * t[3];
    *reinterpret_cast<float4*>(out + (size_t)p) = o;
}

extern "C" void kernel_launch(void* const* d_in, const int* in_sizes, int n_in,
                              void* d_out, int out_size, void* d_ws, size_t ws_size,
                              hipStream_t stream) {
    const float* x = (const float*)d_in[0];
    // d_in[1] = params (always 1 here; params==0 changes output shape, impossible
    // given out_size)
    const int* idx = (const int*)d_in[2];
    float* out = (float*)d_out;

    char* ws = (char*)d_ws;
    unsigned int* weakb = (unsigned int*)ws;                 // 1 MB
    unsigned int* strongb = (unsigned int*)(ws + 1048576);   // 1 MB

    // d_out regions (dead until mul overwrites): flag bitmap, counter, list
    char* ob = (char*)d_out;
    unsigned int* flagb = (unsigned int*)ob;                 // [0, 1MB)
    unsigned int* fcount = (unsigned int*)(ob + 1048576);    // 4 B
    unsigned int* flist = (unsigned int*)(ob + 2097152);     // [2MB, 3MB)

    hipMemsetAsync(fcount, 0, 4, stream);

    int ntiles = KCH * NT * NT;  // 8192
    canny_fused<<<ntiles, 256, 0, stream>>>(x, idx, weakb, strongb, flagb);
    compact_kernel<<<(KCH * WORDS) / 256, 256, 0, stream>>>(flagb, fcount, flist);
    fixup_kernel<<<LISTCAP / 256, 256, 0, stream>>>(x, idx, fcount, flist, weakb, strongb);
    hyst_iterate<<<KCH, 1024, 0, stream>>>(weakb, strongb);
    mul_kernel<<<(KCH * HW / 4) / 256, 256, 0, stream>>>(x, idx, weakb, strongb, out);
}

// Round 16
// 66.665 us; speedup vs baseline: 2.7962x; 2.7962x over previous
//
#include <hip/hip_runtime.h>
#include <cstdint>
#include <math.h>

// fp contraction ENABLED (round 9+): f64 FMA vs mul+add differs ~1 ulp;
// decision-flip probability ~1e-13 total. Benched absmax 0.0 (rounds 10,11).

// Canny_1116691497316: per-channel Canny edges, out = x[:,indices] * tf
// x: (1,64,512,512) f32, indices: (32,) int32, out: (1,32,512,512) f32
//
// Round 16: revert to the proven round-11 f64 kernel (67.7 us; the f32+fixup
// fork of rounds 12-15 never beat it) with two surgical tweaks:
//   (a) inline reflect in the load loop -> drops rmap/cmap tables AND the
//       first block barrier (clamp tables' first consumer is 3 barriers later);
//   (b) bl stride 36->37, sq stride 34->35 (bank-aliasing relief), fitting the
//       same 23552-B LDS granule -> occupancy unchanged by construction.
// Pipeline: canny_fused -> hyst_iterate -> mul. d_ws = 2 MB bitmaps.

constexpr int HH = 512;
constexpr int WW = 512;
constexpr int HW = HH * WW;          // 262144 px per channel
constexpr int KCH = 32;              // selected channels
constexpr int WORDS = HW / 32;       // 8192 uint32 words per bitmap per channel

constexpr int TD = 32;               // tile dim (32x32 output px)
constexpr int NT = HH / TD;          // 16 tiles per side, 256 per channel

constexpr int IN_D = 40;             // input tile 40x40 (halo 4), stride 40
constexpr int VP_C = 40;             // vp tile 36x40, stride 40
constexpr int BL_P = 37;             // blur tile 36x36, stride 37 (padded)
constexpr int SQ_P = 35;             // mag^2 tile 34x34, stride 35 (padded)

// f64 gaussian weights, exact value chain of the reference:
// g_i = exp(-0.5*t^2), s = ((((g0+g1)+g2)+g3)+g4), w_i = g_i/s (IEEE f64)
constexpr double E2 = 0.13533528323661269189;  // exp(-2.0), correctly rounded
constexpr double E1 = 0.60653065971263342360;  // exp(-0.5), correctly rounded
constexpr double GS = ((((E2 + E1) + 1.0) + E1) + E2);
constexpr double GW0 = E2 / GS, GW1 = E1 / GS, GW2 = 1.0 / GS;

// tan(22.5deg) = sqrt(2)-1, tan(67.5deg) = sqrt(2)+1
constexpr double T1 = 0.4142135623730950488;
constexpr double T2 = 2.4142135623730950488;

// squared thresholds: m > thr  <=>  m^2 > thr^2 (up to ~1-ulp sqrt band)
constexpr double SQ_HI = 0.2 * 0.2;
constexpr double SQ_LO = 0.1 * 0.1;

__device__ __forceinline__ int reflect_idx(int v) {
    // jnp.pad mode='reflect', N=512 (valid for overhang <= 4 here)
    return v < 0 ? -v : (v > 511 ? 1022 - v : v);
}
__device__ __forceinline__ int clampi(int v) {
    return v < 0 ? 0 : (v > 511 ? 511 : v);
}

// axis a in {0..3}: NMS neighbor pair, == rint(atan2(gy,gx)*(180/pi)/45) mod 4
__device__ const int AY1[4] = {0, 1, 1, 1};
__device__ const int AX1[4] = {1, 1, 0, -1};

// ---------------- Kernel 1: fused blur + sobel + mag^2 + NMS + thresholds ----------------
// One 256-thread block per 32x32 output tile. LDS overlay (23,336 B, same
// 23,552-B granule as round 11):
//   [0, 11520):      vp f64[36 x 40] -> later sq f64[34 x stride 35] overlay
//   [11520, 22176):  in f32[40 x 40] -> later bl f64[36 x stride 37] overlay
//   [22176, 23200):  ax u8[32*32]
//   [23200, 23336):  clamp tables RU/RD/CL/CR u8[34] x4
__global__ __launch_bounds__(256) void canny_fused(const float* __restrict__ x,
                                                   const int* __restrict__ idx,
                                                   unsigned int* __restrict__ weakb,
                                                   unsigned int* __restrict__ strongb) {
    __shared__ __align__(16) char lds[23336];
    double* vp_s = (double*)lds;                           // [36*40]
    double* sq_s = (double*)lds;                           // [34*35] overlay (vp dead)
    float*  in_s = (float*)(lds + 11520);                  // [40*40]
    double* bl_s = (double*)(lds + 11520);                 // [36*37] overlay (in dead)
    unsigned char* ax_s = (unsigned char*)(lds + 22176);   // [32*32]
    unsigned char* RUm = (unsigned char*)(lds + 23200);    // [34]
    unsigned char* RDm = RUm + 34;                         // [34]
    unsigned char* CLm = RUm + 68;                         // [34]
    unsigned char* CRm = RUm + 102;                        // [34]

    int tile = blockIdx.x;
    int k = tile >> 8;                 // 256 tiles per channel
    int t = tile & 255;
    int ty0 = (t >> 4) * TD;
    int tx0 = (t & 15) * TD;
    int tid = threadIdx.x;

    int ch = idx[k];
    const float* img = x + (size_t)ch * HW;

    // ---- clamp tables (first consumed in the mag pass, 3 barriers later) ----
    if (tid >= 64 && tid < 98) {
        int am = tid - 64;
        int u = ty0 - 1 + am;
        RUm[am] = (unsigned char)(clampi(u - 1) - (ty0 - 2));
        RDm[am] = (unsigned char)(clampi(u + 1) - (ty0 - 2));
    } else if (tid >= 128 && tid < 162) {
        int bm = tid - 128;
        int v = tx0 - 1 + bm;
        CLm[bm] = (unsigned char)(clampi(v - 1) - (tx0 - 2));
        CRm[bm] = (unsigned char)(clampi(v + 1) - (tx0 - 2));
    }

    // ---- load input tile 40x40, inline reflect (no table dependency) ----
    {
        int a = tid / 40, b = tid - (tid / 40) * 40;   // one division
        while (a < 40) {
            in_s[a * IN_D + b] = img[reflect_idx(ty0 - 4 + a) * WW + reflect_idx(tx0 - 4 + b)];
            b += 16; a += 6;
            if (b >= 40) { b -= 40; a += 1; }
        }
    }
    __syncthreads();   // covers in_s AND clamp-table writes

    const double g[5] = {GW0, GW1, GW2, GW1, GW0};

    // ---- vertical blur: sliding window, 6 cells/thread; lanes are
    //      CONSECUTIVE COLUMNS (bank-conflict-free reads & writes) ----
    if (tid < 240) {
        int rg = tid / 40;           // row group 0..5
        int b  = tid - 40 * rg;      // column 0..39 (lane-major)
        int a0 = 6 * rg;             // row base
        double w[10];
        #pragma unroll
        for (int j = 0; j < 10; j++) w[j] = (double)in_s[(a0 + j) * IN_D + b];
        #pragma unroll
        for (int i = 0; i < 6; i++) {
            double acc = g[0] * w[i];
            acc += g[1] * w[i + 1];
            acc += g[2] * w[i + 2];
            acc += g[3] * w[i + 3];
            acc += g[4] * w[i + 4];
            vp_s[(a0 + i) * VP_C + b] = acc;
        }
    }
    __syncthreads();

    // ---- horizontal blur: per-cell linear (consecutive f64 reads) ----
    // (bl overlays in_s, which is dead after the vertical pass)
    {
        int a = tid / 36, b = tid - 36 * (tid / 36);   // one division
        while (a < 36) {
            const double* vr = vp_s + a * VP_C + b;
            double acc = g[0] * vr[0];
            acc += g[1] * vr[1];
            acc += g[2] * vr[2];
            acc += g[3] * vr[3];
            acc += g[4] * vr[4];
            bl_s[a * BL_P + b] = acc;
            b += 4; a += 7;                            // step 256 = 7*36 + 4
            if (b >= 36) { b -= 36; a += 1; }
        }
    }
    __syncthreads();   // fences vp reads before sq overlay writes

    // ---- mag^2 + axis: sobel (clamp tables) on bl, 34x34 ----
    {
        int am = tid / 34, bm = tid - 34 * (tid / 34);   // one division
        while (am < 34) {
            int ru = RUm[am], r0 = am + 1, rd = RDm[am];
            int cl = CLm[bm], c0 = bm + 1, cr = CRm[bm];
            double v00 = bl_s[ru * BL_P + cl], v01 = bl_s[ru * BL_P + c0], v02 = bl_s[ru * BL_P + cr];
            double v10 = bl_s[r0 * BL_P + cl],                              v12 = bl_s[r0 * BL_P + cr];
            double v20 = bl_s[rd * BL_P + cl], v21 = bl_s[rd * BL_P + c0], v22 = bl_s[rd * BL_P + cr];
            double gxv = ((((-v00 + v02) + (-2.0 * v10)) + (2.0 * v12)) + (-v20)) + v22;
            double gyv = ((((-v00 + (-2.0 * v01)) + (-v02)) + v20) + (2.0 * v21)) + v22;
            sq_s[am * SQ_P + bm] = (gxv * gxv + gyv * gyv) + 1e-6;

            // sector: fold gy<0; compare |gy| vs tan boundaries (rounds 5-11 logic)
            double axv = fabs(gxv), ayv = fabs(gyv);
            int axis;
            if (ayv < T1 * axv) axis = 0;
            else if (ayv > T2 * axv) axis = 2;
            else {
                double gxf = (gyv < 0.0) ? -gxv : gxv;
                axis = (gxf > 0.0) ? 1 : 3;
            }
            if (am >= 1 && am <= TD && bm >= 1 && bm <= TD)
                ax_s[(am - 1) * TD + (bm - 1)] = (unsigned char)axis;

            bm += 18; am += 7;                    // step 256 = 7*34 + 18
            if (bm >= 34) { bm -= 34; am += 1; }
        }
    }
    __syncthreads();

    // ---- NMS + double threshold + ballot (squared domain) ----
    // 64-lane wave spans 2 image rows x 32 cols; write ballots as two u32 halves.
    #pragma unroll
    for (int q4 = 0; q4 < TD * TD / 256; q4++) {
        int l = q4 * 256 + tid;
        int oy = l >> 5, ox = l & 31;
        int gy = ty0 + oy, gx = tx0 + ox;

        int axis = ax_s[oy * TD + ox];
        int dy = AY1[axis], dx = AX1[axis];
        double s = sq_s[(oy + 1) * SQ_P + (ox + 1)];

        int y1 = gy + dy, x1 = gx + dx;
        int y2 = gy - dy, x2 = gx - dx;
        // NMS conv zero-padded: out-of-image neighbor contributes 0
        double s1 = (y1 >= 0 && y1 < HH && x1 >= 0 && x1 < WW)
                        ? sq_s[(oy + 1 + dy) * SQ_P + (ox + 1 + dx)] : 0.0;
        double s2 = (y2 >= 0 && y2 < HH && x2 >= 0 && x2 < WW)
                        ? sq_s[(oy + 1 - dy) * SQ_P + (ox + 1 - dx)] : 0.0;
        bool keep = (s > s1) && (s > s2);

        bool strong = keep && (s > SQ_HI);
        bool weak = keep && (s > SQ_LO) && !strong;

        unsigned long long wb = __ballot(weak);
        unsigned long long sb = __ballot(strong);
        if ((tid & 31) == 0) {
            unsigned int ww = (tid & 32) ? (unsigned int)(wb >> 32) : (unsigned int)wb;
            unsigned int sw = (tid & 32) ? (unsigned int)(sb >> 32) : (unsigned int)sb;
            size_t w32 = ((size_t)k * HW + (size_t)gy * WW + tx0) >> 5;
            weakb[w32] = ww;
            strongb[w32] = sw;
        }
    }
}

// ---------------- Kernel 2: hysteresis closure on bitmaps ----------------
// One block per channel; strong bitmap in LDS; monotone 3x3 bitwise dilation
// through the weak mask until fixed point (== reference while_loop fixed point).
__global__ __launch_bounds__(1024) void hyst_iterate(const unsigned int* __restrict__ weakb,
                                                     unsigned int* __restrict__ strongb) {
    int k = blockIdx.x;
    __shared__ unsigned int Sm[WORDS];
    __shared__ int s_changed;
    int tid = threadIdx.x;

    const unsigned int* wsrc = weakb + (size_t)k * WORDS;
    unsigned int* ssrc = strongb + (size_t)k * WORDS;

    if (tid == 0) s_changed = 0;
    for (int i = tid; i < WORDS; i += 1024) Sm[i] = ssrc[i];
    unsigned int wreg[8];
    #pragma unroll
    for (int q = 0; q < 8; q++) wreg[q] = wsrc[tid * 8 + q];
    __syncthreads();

    for (;;) {
        int loc = 0;
        #pragma unroll
        for (int q = 0; q < 8; q++) {
            int w = tid * 8 + q;
            unsigned int s = Sm[w];
            unsigned int wk = wreg[q] & ~s;
            if (!wk) continue;
            int j = w & 15;  // word column within 16-word row
            unsigned int L = j ? Sm[w - 1] : 0u;
            unsigned int R = (j < 15) ? Sm[w + 1] : 0u;
            unsigned int D = (s << 1) | (L >> 31) | (s >> 1) | (R << 31);
            if (w >= 16) {
                unsigned int cu = Sm[w - 16];
                unsigned int Lu = j ? Sm[w - 17] : 0u;
                unsigned int Ru = (j < 15) ? Sm[w - 15] : 0u;
                D |= cu | (cu << 1) | (Lu >> 31) | (cu >> 1) | (Ru << 31);
            }
            if (w < WORDS - 16) {
                unsigned int cd = Sm[w + 16];
                unsigned int Ld = j ? Sm[w + 15] : 0u;
                unsigned int Rd = (j < 15) ? Sm[w + 17] : 0u;
                D |= cd | (cd << 1) | (Ld >> 31) | (cd >> 1) | (Rd << 31);
            }
            unsigned int promoted = wk & D;
            if (promoted) { Sm[w] = s | promoted; loc = 1; }
        }
        if (loc) s_changed = 1;
        __syncthreads();
        int chg = s_changed;
        __syncthreads();
        if (!chg) break;
        if (tid == 0) s_changed = 0;
        __syncthreads();
    }

    for (int i = tid; i < WORDS; i += 1024) ssrc[i] = Sm[i];
}

// ---------------- Kernel 3: out = x[:,indices] * tf, full grid, float4 ----------------
__global__ void mul_kernel(const float* __restrict__ x,
                           const int* __restrict__ idx,
                           const unsigned int* __restrict__ weakb,
                           const unsigned int* __restrict__ strongb,
                           float* __restrict__ out) {
    int gid = blockIdx.x * blockDim.x + threadIdx.x;
    int p = gid * 4;
    if (p >= KCH * HW) return;
    int k = p >> 18;
    int r = p & (HW - 1);
    int ch = idx[k];

    unsigned int sw = strongb[p >> 5];
    unsigned int ww = weakb[p >> 5];
    int b0 = p & 31;

    const float4 xv = *reinterpret_cast<const float4*>(x + (size_t)ch * HW + r);
    float t[4];
    #pragma unroll
    for (int i = 0; i < 4; i++) {
        int b = b0 + i;
        t[i] = ((sw >> b) & 1u) ? 1.0f : (((ww >> b) & 1u) ? 0.5f : 0.0f);
    }
    float4 o;
    o.x = xv.x * t[0];
    o.y = xv.y * t[1];
    o.z = xv.z * t[2];
    o.w = xv.w * t[3];
    *reinterpret_cast<float4*>(out + (size_t)p) = o;
}

extern "C" void kernel_launch(void* const* d_in, const int* in_sizes, int n_in,
                              void* d_out, int out_size, void* d_ws, size_t ws_size,
                              hipStream_t stream) {
    const float* x = (const float*)d_in[0];
    // d_in[1] = params (always 1 here; params==0 changes output shape, impossible
    // given out_size)
    const int* idx = (const int*)d_in[2];
    float* out = (float*)d_out;

    char* ws = (char*)d_ws;
    unsigned int* weakb = (unsigned int*)ws;                 // 1 MB
    unsigned int* strongb = (unsigned int*)(ws + 1048576);   // 1 MB

    int ntiles = KCH * NT * NT;  // 8192
    canny_fused<<<ntiles, 256, 0, stream>>>(x, idx, weakb, strongb);
    hyst_iterate<<<KCH, 1024, 0, stream>>>(weakb, strongb);
    mul_kernel<<<(KCH * HW / 4) / 256, 256, 0, stream>>>(x, idx, weakb, strongb, out);
}

// Round 17
// 63.842 us; speedup vs baseline: 2.9199x; 1.0442x over previous
//
#include <hip/hip_runtime.h>
#include <cstdint>
#include <math.h>

// fp contraction ENABLED (round 9+): f64 FMA vs mul+add differs ~1 ulp;
// decision-flip probability ~1e-13 total. Benched absmax 0.0 (rounds 10,11,16).

// Canny_1116691497316: per-channel Canny edges, out = x[:,indices] * tf
// x: (1,64,512,512) f32, indices: (32,) int32, out: (1,32,512,512) f32
//
// Round 17: LDS repack only (value chains byte-identical to round 16):
// ax_s moved into region0's dead vp tail (written post-h-blur barrier where
// vp is dead) -> LDS 23336 -> 22312 B -> granule 22528 -> 7 blocks/CU (was 6).
// Pipeline: canny_fused -> hyst_iterate -> mul. d_ws = 2 MB bitmaps.

constexpr int HH = 512;
constexpr int WW = 512;
constexpr int HW = HH * WW;          // 262144 px per channel
constexpr int KCH = 32;              // selected channels
constexpr int WORDS = HW / 32;       // 8192 uint32 words per bitmap per channel

constexpr int TD = 32;               // tile dim (32x32 output px)
constexpr int NT = HH / TD;          // 16 tiles per side, 256 per channel

constexpr int IN_D = 40;             // input tile 40x40 (halo 4), stride 40
constexpr int VP_C = 40;             // vp tile 36x40, stride 40
constexpr int BL_P = 37;             // blur tile 36x36, stride 37 (padded)
constexpr int SQ_P = 35;             // mag^2 tile 34x34, stride 35 (padded)

// f64 gaussian weights, exact value chain of the reference:
// g_i = exp(-0.5*t^2), s = ((((g0+g1)+g2)+g3)+g4), w_i = g_i/s (IEEE f64)
constexpr double E2 = 0.13533528323661269189;  // exp(-2.0), correctly rounded
constexpr double E1 = 0.60653065971263342360;  // exp(-0.5), correctly rounded
constexpr double GS = ((((E2 + E1) + 1.0) + E1) + E2);
constexpr double GW0 = E2 / GS, GW1 = E1 / GS, GW2 = 1.0 / GS;

// tan(22.5deg) = sqrt(2)-1, tan(67.5deg) = sqrt(2)+1
constexpr double T1 = 0.4142135623730950488;
constexpr double T2 = 2.4142135623730950488;

// squared thresholds: m > thr  <=>  m^2 > thr^2 (up to ~1-ulp sqrt band)
constexpr double SQ_HI = 0.2 * 0.2;
constexpr double SQ_LO = 0.1 * 0.1;

__device__ __forceinline__ int reflect_idx(int v) {
    // jnp.pad mode='reflect', N=512 (valid for overhang <= 4 here)
    return v < 0 ? -v : (v > 511 ? 1022 - v : v);
}
__device__ __forceinline__ int clampi(int v) {
    return v < 0 ? 0 : (v > 511 ? 511 : v);
}

// axis a in {0..3}: NMS neighbor pair, == rint(atan2(gy,gx)*(180/pi)/45) mod 4
__device__ const int AY1[4] = {0, 1, 1, 1};
__device__ const int AX1[4] = {1, 1, 0, -1};

// ---------------- Kernel 1: fused blur + sobel + mag^2 + NMS + thresholds ----------------
// One 256-thread block per 32x32 output tile. LDS overlay (22,312 B -> 7 blocks/CU):
//   [0, 11520):      vp f64[36 x 40]; after h-blur barrier vp is DEAD and the
//                    region is re-used as sq f64[34 x stride 35] ([0,9520)) +
//                    ax u8[32*32] ([9520,10544))
//   [11520, 22176):  in f32[40 x 40] -> bl f64[36 x stride 37] overlay (in dead)
//   [22176, 22312):  clamp tables RU/RD/CL/CR u8[34] x4 (never overlaid)
__global__ __launch_bounds__(256) void canny_fused(const float* __restrict__ x,
                                                   const int* __restrict__ idx,
                                                   unsigned int* __restrict__ weakb,
                                                   unsigned int* __restrict__ strongb) {
    __shared__ __align__(16) char lds[22312];
    double* vp_s = (double*)lds;                           // [36*40]
    double* sq_s = (double*)lds;                           // [34*35] overlay (vp dead)
    unsigned char* ax_s = (unsigned char*)(lds + 9520);    // [32*32] overlay (vp dead)
    float*  in_s = (float*)(lds + 11520);                  // [40*40]
    double* bl_s = (double*)(lds + 11520);                 // [36*37] overlay (in dead)
    unsigned char* RUm = (unsigned char*)(lds + 22176);    // [34]
    unsigned char* RDm = RUm + 34;                         // [34]
    unsigned char* CLm = RUm + 68;                         // [34]
    unsigned char* CRm = RUm + 102;                        // [34]

    int tile = blockIdx.x;
    int k = tile >> 8;                 // 256 tiles per channel
    int t = tile & 255;
    int ty0 = (t >> 4) * TD;
    int tx0 = (t & 15) * TD;
    int tid = threadIdx.x;

    int ch = idx[k];
    const float* img = x + (size_t)ch * HW;

    // ---- clamp tables (first consumed in the mag pass, 3 barriers later) ----
    if (tid >= 64 && tid < 98) {
        int am = tid - 64;
        int u = ty0 - 1 + am;
        RUm[am] = (unsigned char)(clampi(u - 1) - (ty0 - 2));
        RDm[am] = (unsigned char)(clampi(u + 1) - (ty0 - 2));
    } else if (tid >= 128 && tid < 162) {
        int bm = tid - 128;
        int v = tx0 - 1 + bm;
        CLm[bm] = (unsigned char)(clampi(v - 1) - (tx0 - 2));
        CRm[bm] = (unsigned char)(clampi(v + 1) - (tx0 - 2));
    }

    // ---- load input tile 40x40, inline reflect (no table dependency) ----
    {
        int a = tid / 40, b = tid - (tid / 40) * 40;   // one division
        while (a < 40) {
            in_s[a * IN_D + b] = img[reflect_idx(ty0 - 4 + a) * WW + reflect_idx(tx0 - 4 + b)];
            b += 16; a += 6;
            if (b >= 40) { b -= 40; a += 1; }
        }
    }
    __syncthreads();   // covers in_s AND clamp-table writes

    const double g[5] = {GW0, GW1, GW2, GW1, GW0};

    // ---- vertical blur: sliding window, 6 cells/thread; lanes are
    //      CONSECUTIVE COLUMNS (bank-conflict-free reads & writes) ----
    if (tid < 240) {
        int rg = tid / 40;           // row group 0..5
        int b  = tid - 40 * rg;      // column 0..39 (lane-major)
        int a0 = 6 * rg;             // row base
        double w[10];
        #pragma unroll
        for (int j = 0; j < 10; j++) w[j] = (double)in_s[(a0 + j) * IN_D + b];
        #pragma unroll
        for (int i = 0; i < 6; i++) {
            double acc = g[0] * w[i];
            acc += g[1] * w[i + 1];
            acc += g[2] * w[i + 2];
            acc += g[3] * w[i + 3];
            acc += g[4] * w[i + 4];
            vp_s[(a0 + i) * VP_C + b] = acc;
        }
    }
    __syncthreads();

    // ---- horizontal blur: per-cell linear (consecutive f64 reads) ----
    // (bl overlays in_s, which is dead after the vertical pass)
    {
        int a = tid / 36, b = tid - 36 * (tid / 36);   // one division
        while (a < 36) {
            const double* vr = vp_s + a * VP_C + b;
            double acc = g[0] * vr[0];
            acc += g[1] * vr[1];
            acc += g[2] * vr[2];
            acc += g[3] * vr[3];
            acc += g[4] * vr[4];
            bl_s[a * BL_P + b] = acc;
            b += 4; a += 7;                            // step 256 = 7*36 + 4
            if (b >= 36) { b -= 36; a += 1; }
        }
    }
    __syncthreads();   // vp dead past here; sq+ax overlay region0

    // ---- mag^2 + axis: sobel (clamp tables) on bl, 34x34 ----
    {
        int am = tid / 34, bm = tid - 34 * (tid / 34);   // one division
        while (am < 34) {
            int ru = RUm[am], r0 = am + 1, rd = RDm[am];
            int cl = CLm[bm], c0 = bm + 1, cr = CRm[bm];
            double v00 = bl_s[ru * BL_P + cl], v01 = bl_s[ru * BL_P + c0], v02 = bl_s[ru * BL_P + cr];
            double v10 = bl_s[r0 * BL_P + cl],                              v12 = bl_s[r0 * BL_P + cr];
            double v20 = bl_s[rd * BL_P + cl], v21 = bl_s[rd * BL_P + c0], v22 = bl_s[rd * BL_P + cr];
            double gxv = ((((-v00 + v02) + (-2.0 * v10)) + (2.0 * v12)) + (-v20)) + v22;
            double gyv = ((((-v00 + (-2.0 * v01)) + (-v02)) + v20) + (2.0 * v21)) + v22;
            sq_s[am * SQ_P + bm] = (gxv * gxv + gyv * gyv) + 1e-6;

            // sector: fold gy<0; compare |gy| vs tan boundaries (rounds 5-16 logic)
            double axv = fabs(gxv), ayv = fabs(gyv);
            int axis;
            if (ayv < T1 * axv) axis = 0;
            else if (ayv > T2 * axv) axis = 2;
            else {
                double gxf = (gyv < 0.0) ? -gxv : gxv;
                axis = (gxf > 0.0) ? 1 : 3;
            }
            if (am >= 1 && am <= TD && bm >= 1 && bm <= TD)
                ax_s[(am - 1) * TD + (bm - 1)] = (unsigned char)axis;

            bm += 18; am += 7;                    // step 256 = 7*34 + 18
            if (bm >= 34) { bm -= 34; am += 1; }
        }
    }
    __syncthreads();

    // ---- NMS + double threshold + ballot (squared domain) ----
    // 64-lane wave spans 2 image rows x 32 cols; write ballots as two u32 halves.
    #pragma unroll
    for (int q4 = 0; q4 < TD * TD / 256; q4++) {
        int l = q4 * 256 + tid;
        int oy = l >> 5, ox = l & 31;
        int gy = ty0 + oy, gx = tx0 + ox;

        int axis = ax_s[oy * TD + ox];
        int dy = AY1[axis], dx = AX1[axis];
        double s = sq_s[(oy + 1) * SQ_P + (ox + 1)];

        int y1 = gy + dy, x1 = gx + dx;
        int y2 = gy - dy, x2 = gx - dx;
        // NMS conv zero-padded: out-of-image neighbor contributes 0
        double s1 = (y1 >= 0 && y1 < HH && x1 >= 0 && x1 < WW)
                        ? sq_s[(oy + 1 + dy) * SQ_P + (ox + 1 + dx)] : 0.0;
        double s2 = (y2 >= 0 && y2 < HH && x2 >= 0 && x2 < WW)
                        ? sq_s[(oy + 1 - dy) * SQ_P + (ox + 1 - dx)] : 0.0;
        bool keep = (s > s1) && (s > s2);

        bool strong = keep && (s > SQ_HI);
        bool weak = keep && (s > SQ_LO) && !strong;

        unsigned long long wb = __ballot(weak);
        unsigned long long sb = __ballot(strong);
        if ((tid & 31) == 0) {
            unsigned int ww = (tid & 32) ? (unsigned int)(wb >> 32) : (unsigned int)wb;
            unsigned int sw = (tid & 32) ? (unsigned int)(sb >> 32) : (unsigned int)sb;
            size_t w32 = ((size_t)k * HW + (size_t)gy * WW + tx0) >> 5;
            weakb[w32] = ww;
            strongb[w32] = sw;
        }
    }
}

// ---------------- Kernel 2: hysteresis closure on bitmaps ----------------
// One block per channel; strong bitmap in LDS; monotone 3x3 bitwise dilation
// through the weak mask until fixed point (== reference while_loop fixed point).
__global__ __launch_bounds__(1024) void hyst_iterate(const unsigned int* __restrict__ weakb,
                                                     unsigned int* __restrict__ strongb) {
    int k = blockIdx.x;
    __shared__ unsigned int Sm[WORDS];
    __shared__ int s_changed;
    int tid = threadIdx.x;

    const unsigned int* wsrc = weakb + (size_t)k * WORDS;
    unsigned int* ssrc = strongb + (size_t)k * WORDS;

    if (tid == 0) s_changed = 0;
    for (int i = tid; i < WORDS; i += 1024) Sm[i] = ssrc[i];
    unsigned int wreg[8];
    #pragma unroll
    for (int q = 0; q < 8; q++) wreg[q] = wsrc[tid * 8 + q];
    __syncthreads();

    for (;;) {
        int loc = 0;
        #pragma unroll
        for (int q = 0; q < 8; q++) {
            int w = tid * 8 + q;
            unsigned int s = Sm[w];
            unsigned int wk = wreg[q] & ~s;
            if (!wk) continue;
            int j = w & 15;  // word column within 16-word row
            unsigned int L = j ? Sm[w - 1] : 0u;
            unsigned int R = (j < 15) ? Sm[w + 1] : 0u;
            unsigned int D = (s << 1) | (L >> 31) | (s >> 1) | (R << 31);
            if (w >= 16) {
                unsigned int cu = Sm[w - 16];
                unsigned int Lu = j ? Sm[w - 17] : 0u;
                unsigned int Ru = (j < 15) ? Sm[w - 15] : 0u;
                D |= cu | (cu << 1) | (Lu >> 31) | (cu >> 1) | (Ru << 31);
            }
            if (w < WORDS - 16) {
                unsigned int cd = Sm[w + 16];
                unsigned int Ld = j ? Sm[w + 15] : 0u;
                unsigned int Rd = (j < 15) ? Sm[w + 17] : 0u;
                D |= cd | (cd << 1) | (Ld >> 31) | (cd >> 1) | (Rd << 31);
            }
            unsigned int promoted = wk & D;
            if (promoted) { Sm[w] = s | promoted; loc = 1; }
        }
        if (loc) s_changed = 1;
        __syncthreads();
        int chg = s_changed;
        __syncthreads();
        if (!chg) break;
        if (tid == 0) s_changed = 0;
        __syncthreads();
    }

    for (int i = tid; i < WORDS; i += 1024) ssrc[i] = Sm[i];
}

// ---------------- Kernel 3: out = x[:,indices] * tf, full grid, float4 ----------------
__global__ void mul_kernel(const float* __restrict__ x,
                           const int* __restrict__ idx,
                           const unsigned int* __restrict__ weakb,
                           const unsigned int* __restrict__ strongb,
                           float* __restrict__ out) {
    int gid = blockIdx.x * blockDim.x + threadIdx.x;
    int p = gid * 4;
    if (p >= KCH * HW) return;
    int k = p >> 18;
    int r = p & (HW - 1);
    int ch = idx[k];

    unsigned int sw = strongb[p >> 5];
    unsigned int ww = weakb[p >> 5];
    int b0 = p & 31;

    const float4 xv = *reinterpret_cast<const float4*>(x + (size_t)ch * HW + r);
    float t[4];
    #pragma unroll
    for (int i = 0; i < 4; i++) {
        int b = b0 + i;
        t[i] = ((sw >> b) & 1u) ? 1.0f : (((ww >> b) & 1u) ? 0.5f : 0.0f);
    }
    float4 o;
    o.x = xv.x * t[0];
    o.y = xv.y * t[1];
    o.z = xv.z * t[2];
    o.w = xv.w * t[3];
    *reinterpret_cast<float4*>(out + (size_t)p) = o;
}

extern "C" void kernel_launch(void* const* d_in, const int* in_sizes, int n_in,
                              void* d_out, int out_size, void* d_ws, size_t ws_size,
                              hipStream_t stream) {
    const float* x = (const float*)d_in[0];
    // d_in[1] = params (always 1 here; params==0 changes output shape, impossible
    // given out_size)
    const int* idx = (const int*)d_in[2];
    float* out = (float*)d_out;

    char* ws = (char*)d_ws;
    unsigned int* weakb = (unsigned int*)ws;                 // 1 MB
    unsigned int* strongb = (unsigned int*)(ws + 1048576);   // 1 MB

    int ntiles = KCH * NT * NT;  // 8192
    canny_fused<<<ntiles, 256, 0, stream>>>(x, idx, weakb, strongb);
    hyst_iterate<<<KCH, 1024, 0, stream>>>(weakb, strongb);
    mul_kernel<<<(KCH * HW / 4) / 256, 256, 0, stream>>>(x, idx, weakb, strongb, out);
}